// Round 1
// baseline (188.702 us; speedup 1.0000x reference)
//
#include <hip/hip_runtime.h>

// Until operator, exact O(T) backward recurrence parallelized as a
// function-composition suffix scan.
//   r[t] = max( min(1, psi[t]), min(phi[t], r[t+1]) ), r[T] = -inf
// Step functions f(x) = max(a, min(b, x)) are closed under composition:
//   (f o g)(x) = max( max(a_f, min(b_f, a_g)), min( min(b_f, b_g), x) )
// One block per batch row b (B=1024); 512 threads x 16 timesteps = T=8192,
// so no cross-block carry. Channels (last dim = 2) ride along as float2.

#define T_LEN 8192
#define K_PER 16      // timesteps per thread
#define BLOCK 512     // threads per block; BLOCK*K_PER == T_LEN

__global__ __launch_bounds__(BLOCK) void until_kernel(
    const float* __restrict__ phi, const float* __restrict__ psi,
    float* __restrict__ out)
{
    const int b   = blockIdx.x;
    const int tid = threadIdx.x;
    const size_t rowBase = (size_t)b * (T_LEN * 2);
    const float4* __restrict__ phi4 = (const float4*)(phi + rowBase);
    const float4* __restrict__ psi4 = (const float4*)(psi + rowBase);
    float4* __restrict__ out4 = (float4*)(out + rowBase);

    const float NEG = -__builtin_huge_valf();
    const float POS =  __builtin_huge_valf();

    // ---- load K_PER timesteps (both channels) into registers ----
    float2 p[K_PER], v[K_PER];
#pragma unroll
    for (int j = 0; j < K_PER / 2; ++j) {
        float4 x = phi4[tid * (K_PER / 2) + j];   // t = tid*K + 2j, 2j+1
        p[2 * j]     = make_float2(x.x, x.y);
        p[2 * j + 1] = make_float2(x.z, x.w);
        float4 y = psi4[tid * (K_PER / 2) + j];
        v[2 * j]     = make_float2(fminf(1.0f, y.x), fminf(1.0f, y.y));
        v[2 * j + 1] = make_float2(fminf(1.0f, y.z), fminf(1.0f, y.w));
    }

    // ---- local composition over the thread's chunk (right-to-left) ----
    // F = f_{t0} o ... o f_{t0+K-1};  A = F(-inf), B = running min of phi
    float2 A  = make_float2(NEG, NEG);
    float2 Bm = make_float2(POS, POS);
#pragma unroll
    for (int j = K_PER - 1; j >= 0; --j) {
        A.x  = fmaxf(v[j].x, fminf(p[j].x, A.x));
        A.y  = fmaxf(v[j].y, fminf(p[j].y, A.y));
        Bm.x = fminf(p[j].x, Bm.x);
        Bm.y = fminf(p[j].y, Bm.y);
    }

    // ---- Hillis-Steele inclusive SUFFIX scan of compositions in LDS ----
    __shared__ float4 sbuf[2][BLOCK];   // {A.x, A.y, B.x, B.y}
    int cur = 0;
    sbuf[0][tid] = make_float4(A.x, A.y, Bm.x, Bm.y);
    __syncthreads();
#pragma unroll
    for (int off = 1; off < BLOCK; off <<= 1) {
        float4 f = sbuf[cur][tid];          // left (applied second)
        float4 r = f;
        if (tid + off < BLOCK) {
            float4 g = sbuf[cur][tid + off]; // right (applied first)
            r.x = fmaxf(f.x, fminf(f.z, g.x));
            r.y = fmaxf(f.y, fminf(f.w, g.y));
            r.z = fminf(f.z, g.z);
            r.w = fminf(f.w, g.w);
        }
        sbuf[cur ^ 1][tid] = r;
        cur ^= 1;
        __syncthreads();
    }

    // carry into this thread = r at t = (tid+1)*K = S[tid+1](-inf) = A[tid+1]
    float2 r;
    if (tid == BLOCK - 1) {
        r = make_float2(NEG, NEG);
    } else {
        float4 s = sbuf[cur][tid + 1];
        r = make_float2(s.x, s.y);
    }

    // ---- replay chunk from carry, emit outputs (float4 = 2 timesteps) ----
    float2 hi;
#pragma unroll
    for (int j = K_PER - 1; j >= 0; --j) {
        r.x = fmaxf(v[j].x, fminf(p[j].x, r.x));
        r.y = fmaxf(v[j].y, fminf(p[j].y, r.y));
        if (j & 1) {
            hi = r;                          // odd timestep -> z,w slot
        } else {
            out4[tid * (K_PER / 2) + (j >> 1)] =
                make_float4(r.x, r.y, hi.x, hi.y);
        }
    }
}

extern "C" void kernel_launch(void* const* d_in, const int* in_sizes, int n_in,
                              void* d_out, int out_size, void* d_ws, size_t ws_size,
                              hipStream_t stream) {
    const float* phi = (const float*)d_in[0];
    const float* psi = (const float*)d_in[1];
    float* out = (float*)d_out;
    const int Bn = in_sizes[0] / (T_LEN * 2);   // = 1024
    until_kernel<<<Bn, BLOCK, 0, stream>>>(phi, psi, out);
}

// Round 2
// 186.610 us; speedup vs baseline: 1.0112x; 1.0112x over previous
//
#include <hip/hip_runtime.h>
#include <math.h>

// Until operator: r[t] = max( min(1,psi[t]), min(phi[t], r[t+1]) ), r[T] = -inf.
// Step functions f(x) = max(a, min(b, x)) are closed under composition:
//   (f o g)(x) = max( max(a_f, min(b_f, a_g)), min( min(b_f, b_g), x) )   [f earlier in time]
// Decomposition (all loads/stores perfectly coalesced, lane = 2 timesteps = 1 float4):
//   block  = one batch row (512 thr = 8 waves, grid = B)
//   wave   = one 1024-step segment
//   iter k = one 128-step chunk; suffix scan across lanes via __shfl_down
// Phase A: segment summaries -> LDS (8 float4). One barrier.
// Phase B: compose right-segment summaries -> scalar carry; re-walk chunks
//          right-to-left (re-reads are L1/L2 warm), apply, store.

#define T_LEN 8192
#define NSEG  8           // segments per row = waves per block
#define BLOCK (NSEG * 64) // 512

__device__ __forceinline__ float rfl(float x) {
    return __int_as_float(__builtin_amdgcn_readfirstlane(__float_as_int(x)));
}

__global__ __launch_bounds__(BLOCK) void until_kernel(
    const float* __restrict__ phi, const float* __restrict__ psi,
    float* __restrict__ out)
{
    const int row  = blockIdx.x;
    const int tid  = threadIdx.x;
    const int w    = tid >> 6;   // segment index within row
    const int lane = tid & 63;

    const float NEG = -__builtin_huge_valf();
    const float POS =  __builtin_huge_valf();

    // float4 = 2 timesteps x 2 channels. Row = 4096 float4s, segment = 512.
    const size_t segf4 = (size_t)row * (T_LEN / 2) + (size_t)w * 512;
    const float4* __restrict__ phi4 = (const float4*)phi + segf4;
    const float4* __restrict__ psi4 = (const float4*)psi + segf4;
    float4* __restrict__ out4 = (float4*)out + segf4;

    __shared__ float4 ssum[NSEG];

    // ---------------- Phase A: segment summary ----------------
    float runAx = NEG, runAy = NEG, runBx = POS, runBy = POS; // identity
#pragma unroll
    for (int k = 0; k < 8; ++k) {
        float4 P = phi4[k * 64 + lane];
        float4 Q = psi4[k * 64 + lane];
        float v0x = fminf(1.f, Q.x), v0y = fminf(1.f, Q.y);
        float v1x = fminf(1.f, Q.z), v1y = fminf(1.f, Q.w);
        // lane function G = f_t0 o f_t1 (2 steps)
        float Gax = fmaxf(v0x, fminf(P.x, v1x));
        float Gay = fmaxf(v0y, fminf(P.y, v1y));
        float Gbx = fminf(P.x, P.z);
        float Gby = fminf(P.y, P.w);
        // ordered suffix scan toward lane 63 (lane0 ends with full chunk)
#pragma unroll
        for (int off = 1; off < 64; off <<= 1) {
            float gax = __shfl_down(Gax, off), gay = __shfl_down(Gay, off);
            float gbx = __shfl_down(Gbx, off), gby = __shfl_down(Gby, off);
            bool val = (lane + off) < 64;
            gax = val ? gax : NEG;  gay = val ? gay : NEG;
            gbx = val ? gbx : POS;  gby = val ? gby : POS;
            Gax = fmaxf(Gax, fminf(Gbx, gax));
            Gay = fmaxf(Gay, fminf(Gby, gay));
            Gbx = fminf(Gbx, gbx);
            Gby = fminf(Gby, gby);
        }
        // chunk summary = lane0's scanned value; broadcast; run = run o chunk
        float cax = rfl(Gax), cay = rfl(Gay), cbx = rfl(Gbx), cby = rfl(Gby);
        runAx = fmaxf(runAx, fminf(runBx, cax));
        runAy = fmaxf(runAy, fminf(runBy, cay));
        runBx = fminf(runBx, cbx);
        runBy = fminf(runBy, cby);
    }
    if (lane == 0) ssum[w] = make_float4(runAx, runAy, runBx, runBy);
    __syncthreads();

    // ---------------- carry entering this segment's right edge ----------------
    float rex = NEG, rey = NEG;
    for (int j = NSEG - 1; j > w; --j) {
        float4 s = ssum[j];
        rex = fmaxf(s.x, fminf(s.z, rex));
        rey = fmaxf(s.y, fminf(s.w, rey));
    }

    // ---------------- Phase B: apply, right-to-left ----------------
#pragma unroll
    for (int k = 7; k >= 0; --k) {
        float4 P = phi4[k * 64 + lane];
        float4 Q = psi4[k * 64 + lane];
        float v0x = fminf(1.f, Q.x), v0y = fminf(1.f, Q.y);
        float v1x = fminf(1.f, Q.z), v1y = fminf(1.f, Q.w);
        float Gax = fmaxf(v0x, fminf(P.x, v1x));
        float Gay = fmaxf(v0y, fminf(P.y, v1y));
        float Gbx = fminf(P.x, P.z);
        float Gby = fminf(P.y, P.w);
#pragma unroll
        for (int off = 1; off < 64; off <<= 1) {
            float gax = __shfl_down(Gax, off), gay = __shfl_down(Gay, off);
            float gbx = __shfl_down(Gbx, off), gby = __shfl_down(Gby, off);
            bool val = (lane + off) < 64;
            gax = val ? gax : NEG;  gay = val ? gay : NEG;
            gbx = val ? gbx : POS;  gby = val ? gby : POS;
            Gax = fmaxf(Gax, fminf(Gbx, gax));
            Gay = fmaxf(Gay, fminf(Gby, gay));
            Gbx = fminf(Gbx, gbx);
            Gby = fminf(Gby, gby);
        }
        // y_i = (F_i o ... o F_63)(r_end)
        float yx = fmaxf(Gax, fminf(Gbx, rex));
        float yy = fmaxf(Gay, fminf(Gby, rey));
        // carry into lane i's later timestep = y_{i+1} (lane 63: r_end)
        float ynx = __shfl_down(yx, 1), yny = __shfl_down(yy, 1);
        if (lane == 63) { ynx = rex; yny = rey; }
        float r1x = fmaxf(v1x, fminf(P.z, ynx));
        float r1y = fmaxf(v1y, fminf(P.w, yny));
        float r0x = fmaxf(v0x, fminf(P.x, r1x));
        float r0y = fmaxf(v0y, fminf(P.y, r1y));
        out4[k * 64 + lane] = make_float4(r0x, r0y, r1x, r1y);
        // carry entering chunk k's left edge = y_0, broadcast for next iter
        rex = rfl(yx);
        rey = rfl(yy);
    }
}

extern "C" void kernel_launch(void* const* d_in, const int* in_sizes, int n_in,
                              void* d_out, int out_size, void* d_ws, size_t ws_size,
                              hipStream_t stream) {
    const float* phi = (const float*)d_in[0];
    const float* psi = (const float*)d_in[1];
    float* out = (float*)d_out;
    const int Bn = in_sizes[0] / (T_LEN * 2); // = 1024
    until_kernel<<<Bn, BLOCK, 0, stream>>>(phi, psi, out);
}

// Round 3
// 181.588 us; speedup vs baseline: 1.0392x; 1.0277x over previous
//
#include <hip/hip_runtime.h>

// Until operator: r[t] = max( min(1,psi[t]), min(phi[t], r[t+1]) ), r[T] = -inf.
// f(x)=max(a,min(b,x)) closed under composition (f earlier in time):
//   (f o g) : A = max(a_f, min(b_f, a_g)),  B = min(b_f, b_g)
// Layout: float4 = 2 timesteps x 2 channels = one "pair entry".
// block = one row (8 waves); wave = 1024-step segment (512 entries).
// Round r (2 rounds x 4 chunks): build pair-functions G, SoA-transpose through
// a private 4KB LDS region so each lane owns 4 CONTIGUOUS entries, compose
// locally, then ONE 64-lane shuffle suffix-scan per round (52 shuffles/wave
// total vs ~400 in the previous version). Carries written back through the
// same region; outputs from an L2/L3-warm reload (ideal coalescing both ways).

#define T_LEN 8192
#define NSEG  8            // waves per block = segments per row
#define BLOCK (NSEG * 64)  // 512

__device__ __forceinline__ float rfl(float x) {
    return __int_as_float(__builtin_amdgcn_readfirstlane(__float_as_int(x)));
}

__global__ __launch_bounds__(BLOCK) void until_kernel(
    const float* __restrict__ phi, const float* __restrict__ psi,
    float* __restrict__ out)
{
    const int  row  = blockIdx.x;
    const int  tid  = threadIdx.x;
    const int  w    = tid >> 6;
    const int  lane = tid & 63;
    const float NEG = -__builtin_huge_valf();
    const float POS =  __builtin_huge_valf();

    const size_t segf4 = (size_t)row * (T_LEN / 2) + (size_t)w * 512;
    const float4* __restrict__ phi4 = (const float4*)phi + segf4;
    const float4* __restrict__ psi4 = (const float4*)psi + segf4;
    float4* __restrict__ out4 = (float4*)out + segf4;

    // Per-wave private 1024-float region. During transpose rounds:
    //   comp c of G lives at [c*256, c*256+256)   (one round at a time)
    // During apply/output: cx at [0,512), cy at [512,1024), indexed by entry.
    __shared__ alignas(16) float lds[NSEG * 1024];
    __shared__ float4 ssum[NSEG];
    float* wl = lds + w * 1024;

    float4 GAx[2], GAy[2], GBx[2], GBy[2];  // lane's 4 entries per round
    float  Sax[2], Say[2], Sbx[2], Sby[2];  // suffix-scan results per round

#pragma unroll
    for (int r = 0; r < 2; ++r) {
        // ---- build G for 4 chunks, SoA write (stride-4B, conflict-free) ----
#pragma unroll
        for (int kl = 0; kl < 4; ++kl) {
            const int e  = (r * 4 + kl) * 64 + lane;  // segment entry index
            const int El = kl * 64 + lane;            // within-round index
            float4 P = phi4[e];
            float4 Q = psi4[e];
            float v0x = fminf(1.f, Q.x), v0y = fminf(1.f, Q.y);
            float v1x = fminf(1.f, Q.z), v1y = fminf(1.f, Q.w);
            wl[0 * 256 + El] = fmaxf(v0x, fminf(P.x, v1x)); // GAx
            wl[1 * 256 + El] = fmaxf(v0y, fminf(P.y, v1y)); // GAy
            wl[2 * 256 + El] = fminf(P.x, P.z);             // GBx
            wl[3 * 256 + El] = fminf(P.y, P.w);             // GBy
        }
        __syncthreads();
        // ---- transposed read: lane gets 4 contiguous entries (b128) ----
        GAx[r] = *(const float4*)(wl + 0 * 256 + lane * 4);
        GAy[r] = *(const float4*)(wl + 1 * 256 + lane * 4);
        GBx[r] = *(const float4*)(wl + 2 * 256 + lane * 4);
        GBy[r] = *(const float4*)(wl + 3 * 256 + lane * 4);
        __syncthreads();

        // ---- local compose right-to-left: H = G_j0 o G_j1 o G_j2 o G_j3 ----
        float hax = GAx[r].w, hay = GAy[r].w, hbx = GBx[r].w, hby = GBy[r].w;
        hax = fmaxf(GAx[r].z, fminf(GBx[r].z, hax));
        hay = fmaxf(GAy[r].z, fminf(GBy[r].z, hay));
        hbx = fminf(GBx[r].z, hbx);
        hby = fminf(GBy[r].z, hby);
        hax = fmaxf(GAx[r].y, fminf(GBx[r].y, hax));
        hay = fmaxf(GAy[r].y, fminf(GBy[r].y, hay));
        hbx = fminf(GBx[r].y, hbx);
        hby = fminf(GBy[r].y, hby);
        hax = fmaxf(GAx[r].x, fminf(GBx[r].x, hax));
        hay = fmaxf(GAy[r].x, fminf(GBy[r].x, hay));
        hbx = fminf(GBx[r].x, hbx);
        hby = fminf(GBy[r].x, hby);

        // ---- 64-lane inclusive SUFFIX scan (toward lane 63) ----
#pragma unroll
        for (int off = 1; off < 64; off <<= 1) {
            float gax = __shfl_down(hax, off), gay = __shfl_down(hay, off);
            float gbx = __shfl_down(hbx, off), gby = __shfl_down(hby, off);
            bool  val = (lane + off) < 64;
            gax = val ? gax : NEG;  gay = val ? gay : NEG;
            gbx = val ? gbx : POS;  gby = val ? gby : POS;
            hax = fmaxf(hax, fminf(hbx, gax));
            hay = fmaxf(hay, fminf(hby, gay));
            hbx = fminf(hbx, gbx);
            hby = fminf(hby, gby);
        }
        Sax[r] = hax; Say[r] = hay; Sbx[r] = hbx; Sby[r] = hby;
    }

    // ---- segment summary W = R0 o R1 -> ssum; then carry into segment ----
    float R0ax = rfl(Sax[0]), R0ay = rfl(Say[0]);
    float R0bx = rfl(Sbx[0]), R0by = rfl(Sby[0]);
    float R1ax = rfl(Sax[1]), R1ay = rfl(Say[1]);
    float R1bx = rfl(Sbx[1]), R1by = rfl(Sby[1]);
    if (lane == 0) {
        float wax = fmaxf(R0ax, fminf(R0bx, R1ax));
        float way = fmaxf(R0ay, fminf(R0by, R1ay));
        float wbx = fminf(R0bx, R1bx);
        float wby = fminf(R0by, R1by);
        ssum[w] = make_float4(wax, way, wbx, wby);
    }
    __syncthreads();
    float rcx = NEG, rcy = NEG;   // carry entering this segment's right edge
    for (int j = NSEG - 1; j > w; --j) {
        float4 s = ssum[j];
        rcx = fmaxf(s.x, fminf(s.z, rcx));
        rcy = fmaxf(s.y, fminf(s.w, rcy));
    }

    // carries entering each round (round 0 sees round 1 applied first)
    float rinx[2], riny[2];
    rinx[1] = rcx;
    riny[1] = rcy;
    rinx[0] = fmaxf(R1ax, fminf(R1bx, rcx));
    riny[0] = fmaxf(R1ay, fminf(R1by, rcy));

    // ---- per-entry carries (registers) -> LDS (b128, conflict-free) ----
#pragma unroll
    for (int r = 0; r < 2; ++r) {
        // y = value at lane's LEFT edge = S_r[lane](r_in)
        float yx = fmaxf(Sax[r], fminf(Sbx[r], rinx[r]));
        float yy = fmaxf(Say[r], fminf(Sby[r], riny[r]));
        // carry entering lane's rightmost entry = y_{lane+1} (lane63: r_in)
        float cx = __shfl_down(yx, 1), cy = __shfl_down(yy, 1);
        if (lane == 63) { cx = rinx[r]; cy = riny[r]; }
        float4 CX, CY;
        CX.w = cx;
        CY.w = cy;
        CX.z = fmaxf(GAx[r].w, fminf(GBx[r].w, CX.w));
        CY.z = fmaxf(GAy[r].w, fminf(GBy[r].w, CY.w));
        CX.y = fmaxf(GAx[r].z, fminf(GBx[r].z, CX.z));
        CY.y = fmaxf(GAy[r].z, fminf(GBy[r].z, CY.z));
        CX.x = fmaxf(GAx[r].y, fminf(GBx[r].y, CX.y));
        CY.x = fmaxf(GAy[r].y, fminf(GBy[r].y, CY.y));
        *(float4*)(wl +       r * 256 + lane * 4) = CX;  // cx[entry]
        *(float4*)(wl + 512 + r * 256 + lane * 4) = CY;  // cy[entry]
    }
    __syncthreads();

    // ---- emit outputs: coalesced reload (L2/L3-warm) + carry from LDS ----
#pragma unroll
    for (int k = 0; k < 8; ++k) {
        const int e = k * 64 + lane;
        float4 P = phi4[e];
        float4 Q = psi4[e];
        float cx = wl[e];          // r at this entry's right edge (t = 2e+2)
        float cy = wl[512 + e];
        float r1x = fmaxf(fminf(1.f, Q.z), fminf(P.z, cx));
        float r1y = fmaxf(fminf(1.f, Q.w), fminf(P.w, cy));
        float r0x = fmaxf(fminf(1.f, Q.x), fminf(P.x, r1x));
        float r0y = fmaxf(fminf(1.f, Q.y), fminf(P.y, r1y));
        out4[e] = make_float4(r0x, r0y, r1x, r1y);
    }
}

extern "C" void kernel_launch(void* const* d_in, const int* in_sizes, int n_in,
                              void* d_out, int out_size, void* d_ws, size_t ws_size,
                              hipStream_t stream) {
    const float* phi = (const float*)d_in[0];
    const float* psi = (const float*)d_in[1];
    float* out = (float*)d_out;
    const int Bn = in_sizes[0] / (T_LEN * 2);  // = 1024
    until_kernel<<<Bn, BLOCK, 0, stream>>>(phi, psi, out);
}

// Round 4
// 180.333 us; speedup vs baseline: 1.0464x; 1.0070x over previous
//
#include <hip/hip_runtime.h>

// Until operator: r[t] = max( min(1,psi[t]), min(phi[t], r[t+1]) ), r[T] = -inf.
// f(x)=max(a,min(b,x)) closed under composition (f earlier in time):
//   (f o g): A = max(a_f, min(b_f, a_g)), B = min(b_f, b_g)
// float4 = 2 timesteps x 2 channels = one "pair entry". Row = 4096 entries.
// block = one row (8 waves); wave = contiguous 512-entry segment.
//
// R4 structural change vs R3: all 16 global loads issued as ONE burst; the
// SoA transpose (so lanes own contiguous entries) is wave-PRIVATE, so the
// block-wide __syncthreads around it are replaced by wave-level compiler
// fences (DS ops of a wave execute in order in HW). Only ONE real barrier
// remains (cross-wave ssum exchange). LDS 64KB -> 2 blocks/CU, 2 pipelined
// block generations instead of 1 fully-synchronized one.

#define T_LEN 8192
#define NSEG  8            // waves per block = segments per row
#define BLOCK (NSEG * 64)  // 512

__device__ __forceinline__ float rfl(float x) {
    return __int_as_float(__builtin_amdgcn_readfirstlane(__float_as_int(x)));
}

// Wave-level ordering fence for wave-private LDS reuse: prevents the compiler
// from moving LDS accesses across it; HW executes a wave's DS ops in order.
__device__ __forceinline__ void wave_lds_fence() {
    __asm__ volatile("" ::: "memory");
    __builtin_amdgcn_wave_barrier();
    __asm__ volatile("" ::: "memory");
}

__global__ __launch_bounds__(BLOCK, 4) void until_kernel(
    const float* __restrict__ phi, const float* __restrict__ psi,
    float* __restrict__ out)
{
    const int  row  = blockIdx.x;
    const int  tid  = threadIdx.x;
    const int  w    = tid >> 6;
    const int  lane = tid & 63;
    const float NEG = -__builtin_huge_valf();
    const float POS =  __builtin_huge_valf();

    const size_t segf4 = (size_t)row * (T_LEN / 2) + (size_t)w * 512;
    const float4* __restrict__ phi4 = (const float4*)phi + segf4;
    const float4* __restrict__ psi4 = (const float4*)psi + segf4;
    float4* __restrict__ out4 = (float4*)out + segf4;

    // Per-wave private 2048-float region:
    //   G phase:  round r in [r*1024, r*1024+1024): 4 SoA comps x 256 entries
    //   carry phase (reuses round-0 area): CX[e] at wl[e], CY[e] at wl[512+e]
    __shared__ alignas(16) float lds[NSEG * 2048];
    __shared__ float4 ssum[NSEG];
    float* wl = lds + w * 2048;

    // ---- burst: issue all 16 global loads back-to-back ----
    float4 P[8], Q[8];
#pragma unroll
    for (int k = 0; k < 8; ++k) {
        P[k] = phi4[k * 64 + lane];
        Q[k] = psi4[k * 64 + lane];
    }

    // ---- build pair functions G, SoA write (dense, conflict-free) ----
#pragma unroll
    for (int k = 0; k < 8; ++k) {
        const int r  = k >> 2;
        const int kl = k & 3;
        float* base = wl + r * 1024 + kl * 64 + lane;
        float v0x = fminf(1.f, Q[k].x), v0y = fminf(1.f, Q[k].y);
        float v1x = fminf(1.f, Q[k].z), v1y = fminf(1.f, Q[k].w);
        base[0]   = fmaxf(v0x, fminf(P[k].x, v1x));  // GAx
        base[256] = fmaxf(v0y, fminf(P[k].y, v1y));  // GAy
        base[512] = fminf(P[k].x, P[k].z);           // GBx
        base[768] = fminf(P[k].y, P[k].w);           // GBy
    }
    wave_lds_fence();   // wave-private transpose: no block barrier needed

    // ---- transposed read (b128, dense) + compose + suffix scan per round ----
    float4 GAx[2], GAy[2], GBx[2], GBy[2];
    float  Sax[2], Say[2], Sbx[2], Sby[2];
#pragma unroll
    for (int r = 0; r < 2; ++r) {
        const float* rb = wl + r * 1024;
        GAx[r] = *(const float4*)(rb + 0 * 256 + lane * 4);
        GAy[r] = *(const float4*)(rb + 1 * 256 + lane * 4);
        GBx[r] = *(const float4*)(rb + 2 * 256 + lane * 4);
        GBy[r] = *(const float4*)(rb + 3 * 256 + lane * 4);

        // local compose right-to-left: H = G_j0 o G_j1 o G_j2 o G_j3
        float hax = GAx[r].w, hay = GAy[r].w, hbx = GBx[r].w, hby = GBy[r].w;
        hax = fmaxf(GAx[r].z, fminf(GBx[r].z, hax));
        hay = fmaxf(GAy[r].z, fminf(GBy[r].z, hay));
        hbx = fminf(GBx[r].z, hbx);
        hby = fminf(GBy[r].z, hby);
        hax = fmaxf(GAx[r].y, fminf(GBx[r].y, hax));
        hay = fmaxf(GAy[r].y, fminf(GBy[r].y, hay));
        hbx = fminf(GBx[r].y, hbx);
        hby = fminf(GBy[r].y, hby);
        hax = fmaxf(GAx[r].x, fminf(GBx[r].x, hax));
        hay = fmaxf(GAy[r].x, fminf(GBy[r].x, hay));
        hbx = fminf(GBx[r].x, hbx);
        hby = fminf(GBy[r].x, hby);

        // 64-lane inclusive SUFFIX scan (toward lane 63)
#pragma unroll
        for (int off = 1; off < 64; off <<= 1) {
            float gax = __shfl_down(hax, off), gay = __shfl_down(hay, off);
            float gbx = __shfl_down(hbx, off), gby = __shfl_down(hby, off);
            bool  val = (lane + off) < 64;
            gax = val ? gax : NEG;  gay = val ? gay : NEG;
            gbx = val ? gbx : POS;  gby = val ? gby : POS;
            hax = fmaxf(hax, fminf(hbx, gax));
            hay = fmaxf(hay, fminf(hby, gay));
            hbx = fminf(hbx, gbx);
            hby = fminf(hby, gby);
        }
        Sax[r] = hax; Say[r] = hay; Sbx[r] = hbx; Sby[r] = hby;
    }

    // ---- segment summary W = R0 o R1 -> ssum (the ONE real barrier) ----
    float R0ax = rfl(Sax[0]), R0ay = rfl(Say[0]);
    float R0bx = rfl(Sbx[0]), R0by = rfl(Sby[0]);
    float R1ax = rfl(Sax[1]), R1ay = rfl(Say[1]);
    float R1bx = rfl(Sbx[1]), R1by = rfl(Sby[1]);
    if (lane == 0) {
        float wax = fmaxf(R0ax, fminf(R0bx, R1ax));
        float way = fmaxf(R0ay, fminf(R0by, R1ay));
        float wbx = fminf(R0bx, R1bx);
        float wby = fminf(R0by, R1by);
        ssum[w] = make_float4(wax, way, wbx, wby);
    }
    __syncthreads();
    float rcx = NEG, rcy = NEG;   // carry entering this segment's right edge
    for (int j = NSEG - 1; j > w; --j) {
        float4 s = ssum[j];
        rcx = fmaxf(s.x, fminf(s.z, rcx));
        rcy = fmaxf(s.y, fminf(s.w, rcy));
    }

    // carries entering each round (round 0 sees round 1 applied first)
    float rinx[2], riny[2];
    rinx[1] = rcx;
    riny[1] = rcy;
    rinx[0] = fmaxf(R1ax, fminf(R1bx, rcx));
    riny[0] = fmaxf(R1ay, fminf(R1by, rcy));

    // ---- per-entry carries -> wave-private LDS (b128, dense) ----
#pragma unroll
    for (int r = 0; r < 2; ++r) {
        // y = value at lane's LEFT edge = S_r[lane](r_in)
        float yx = fmaxf(Sax[r], fminf(Sbx[r], rinx[r]));
        float yy = fmaxf(Say[r], fminf(Sby[r], riny[r]));
        // carry entering lane's rightmost entry = y_{lane+1} (lane63: r_in)
        float cx = __shfl_down(yx, 1), cy = __shfl_down(yy, 1);
        if (lane == 63) { cx = rinx[r]; cy = riny[r]; }
        float4 CX, CY;
        CX.w = cx;
        CY.w = cy;
        CX.z = fmaxf(GAx[r].w, fminf(GBx[r].w, CX.w));
        CY.z = fmaxf(GAy[r].w, fminf(GBy[r].w, CY.w));
        CX.y = fmaxf(GAx[r].z, fminf(GBx[r].z, CX.z));
        CY.y = fmaxf(GAy[r].z, fminf(GBy[r].z, CY.z));
        CX.x = fmaxf(GAx[r].y, fminf(GBx[r].y, CX.y));
        CY.x = fmaxf(GAy[r].y, fminf(GBy[r].y, CY.y));
        *(float4*)(wl +       r * 256 + lane * 4) = CX;  // CX[e] at wl[e]
        *(float4*)(wl + 512 + r * 256 + lane * 4) = CY;  // CY[e] at wl[512+e]
    }
    wave_lds_fence();   // wave-private carry handoff: no block barrier

    // ---- emit outputs: coalesced reload (L2/L3-warm) + carry from LDS ----
#pragma unroll
    for (int k = 0; k < 8; ++k) {
        const int e = k * 64 + lane;
        float4 P2 = phi4[e];
        float4 Q2 = psi4[e];
        float cx = wl[e];          // r at this entry's right edge
        float cy = wl[512 + e];
        float r1x = fmaxf(fminf(1.f, Q2.z), fminf(P2.z, cx));
        float r1y = fmaxf(fminf(1.f, Q2.w), fminf(P2.w, cy));
        float r0x = fmaxf(fminf(1.f, Q2.x), fminf(P2.x, r1x));
        float r0y = fmaxf(fminf(1.f, Q2.y), fminf(P2.y, r1y));
        out4[e] = make_float4(r0x, r0y, r1x, r1y);
    }
}

extern "C" void kernel_launch(void* const* d_in, const int* in_sizes, int n_in,
                              void* d_out, int out_size, void* d_ws, size_t ws_size,
                              hipStream_t stream) {
    const float* phi = (const float*)d_in[0];
    const float* psi = (const float*)d_in[1];
    float* out = (float*)d_out;
    const int Bn = in_sizes[0] / (T_LEN * 2);  // = 1024
    until_kernel<<<Bn, BLOCK, 0, stream>>>(phi, psi, out);
}